// Round 4
// baseline (169.452 us; speedup 1.0000x reference)
//
#include <hip/hip_runtime.h>

#define GEMM_THREADS 512
#define NBLK 256

typedef float f32x4 __attribute__((ext_vector_type(4)));
typedef short s16x8 __attribute__((ext_vector_type(8)));

__device__ __forceinline__ unsigned short f2bf(float f) {
  union { float f; unsigned u; } v; v.f = f;
  return (unsigned short)((v.u + 0x7FFFu + ((v.u >> 16) & 1u)) >> 16);  // RTNE
}

__global__ void __launch_bounds__(256) zero_kernel(float* out, float* ws, long long nws) {
  long long idx = (long long)blockIdx.x * blockDim.x + threadIdx.x;
  if (idx == 0) out[0] = 0.f;
  for (long long k = idx; k < nws; k += (long long)gridDim.x * blockDim.x) ws[k] = 0.f;
}

// Non-draining barrier: lgkmcnt(0) (LDS visibility) + s_barrier + sched pin.
// Does NOT wait vmcnt -> prefetched global loads stay in flight across it.
__device__ __forceinline__ void barrier_nodrain() {
  asm volatile("s_waitcnt lgkmcnt(0)" ::: "memory");
  __builtin_amdgcn_s_barrier();
  __builtin_amdgcn_sched_barrier(0);
}

// Split-K GEMM, BK=64: block b owns K-chunk [b*KC,(b+1)*KC), computes full
// 256x256 partial into ws + b*65536.
//  - 256 B contiguous per row-visit per step (DRAM page locality, vs 128 B before)
//  - per-block rotated step order (start at step b%ns) to decorrelate the
//    column-window (address bits [7:14)) across blocks -> spread DRAM channels
//  - single 80 KiB LDS buffer [half][mat][256][40], reg-staged one step ahead;
//    two nodrain barriers per step keep loads in flight
__global__ void __launch_bounds__(GEMM_THREADS, 2)
gemm_kernel(const float* __restrict__ V1, const float* __restrict__ V2,
            float* __restrict__ ws, int D, int KC, int P, int useAtomic) {
  __shared__ __align__(16) unsigned short lds[2 * 2 * 256 * 40];  // 80 KiB

  const int tid  = threadIdx.x;
  const int lane = tid & 63;
  const int wid  = tid >> 6;
  const int wm   = wid >> 2;   // 0..1
  const int wn   = wid & 3;    // 0..3
  const int lr   = lane & 15;
  const int lg   = lane >> 4;

  const int c16 = tid & 15;    // 16B segment within a row's 256B step-window
  const int r0  = tid >> 4;    // base row 0..31 (rows r0 + 32q, q=0..7)
  const int ns  = KC >> 6;     // K-steps of 64 (16 for KC=1024)
  const int s0  = (int)(blockIdx.x % (unsigned)ns);   // rotation offset

  f32x4 acc[8][4];
#pragma unroll
  for (int a = 0; a < 8; ++a)
#pragma unroll
    for (int b = 0; b < 4; ++b) acc[a][b] = f32x4{0.f, 0.f, 0.f, 0.f};

  const size_t kb = (size_t)blockIdx.x * (size_t)KC + (size_t)(c16 * 4);
  const float* baseA = V1 + (size_t)r0 * (size_t)D + kb;
  const float* baseB = V2 + (size_t)r0 * (size_t)D + kb;
  const size_t rstride = (size_t)32 * (size_t)D;

  float4 sa[8], sb[8];

  auto issue = [&](int t) {
    const size_t ko = (size_t)(((t + s0) % ns) * 64);
#pragma unroll
    for (int q = 0; q < 8; ++q) {
      sa[q] = *(const float4*)(baseA + (size_t)q * rstride + ko);
      sb[q] = *(const float4*)(baseB + (size_t)q * rstride + ko);
    }
  };
  auto lwrite = [&]() {
    const int h  = c16 >> 3;   // k-half 0/1
    const int c8 = c16 & 7;    // 8B slot within half-row
#pragma unroll
    for (int q = 0; q < 8; ++q) {
      int r  = r0 + 32 * q;
      int ua = ((h * 2 + 0) * 256 + r) * 40 + c8 * 4;
      int ub = ((h * 2 + 1) * 256 + r) * 40 + c8 * 4;
      ushort4 wa, wb;
      wa.x = f2bf(sa[q].x); wa.y = f2bf(sa[q].y); wa.z = f2bf(sa[q].z); wa.w = f2bf(sa[q].w);
      wb.x = f2bf(sb[q].x); wb.y = f2bf(sb[q].y); wb.z = f2bf(sb[q].z); wb.w = f2bf(sb[q].w);
      *(ushort4*)&lds[ua] = wa;
      *(ushort4*)&lds[ub] = wb;
    }
  };

  issue(0);
  lwrite();
  if (ns > 1) issue(1);
  barrier_nodrain();

  for (int t = 0; t < ns; ++t) {
#pragma unroll
    for (int h = 0; h < 2; ++h) {
      s16x8 af[8], bfr[4];
#pragma unroll
      for (int mf = 0; mf < 8; ++mf) {
        int r = wm * 128 + mf * 16 + lr;
        af[mf] = *(const s16x8*)&lds[((h * 2 + 0) * 256 + r) * 40 + lg * 8];
      }
#pragma unroll
      for (int nf = 0; nf < 4; ++nf) {
        int r = wn * 64 + nf * 16 + lr;
        bfr[nf] = *(const s16x8*)&lds[((h * 2 + 1) * 256 + r) * 40 + lg * 8];
      }
#pragma unroll
      for (int mf = 0; mf < 8; ++mf)
#pragma unroll
        for (int nf = 0; nf < 4; ++nf)
          acc[mf][nf] = __builtin_amdgcn_mfma_f32_16x16x32_bf16(af[mf], bfr[nf], acc[mf][nf], 0, 0, 0);
    }
    barrier_nodrain();              // all waves done reading this step
    if (t + 1 < ns) {
      lwrite();                     // waits (reg deps) only batch(t+1), refills LDS
      if (t + 2 < ns) issue(t + 2); // next batch stays in flight across barriers
      barrier_nodrain();            // writes visible before next step's reads
    }
  }

  // C/D layout: col = lane&15, row = (lane>>4)*4 + reg
  float* Cp = ws + (size_t)(blockIdx.x % (unsigned)P) * (256 * 256);
#pragma unroll
  for (int mf = 0; mf < 8; ++mf) {
    int i0 = wm * 128 + mf * 16 + lg * 4;
#pragma unroll
    for (int nf = 0; nf < 4; ++nf) {
      int j = wn * 64 + nf * 16 + lr;
#pragma unroll
      for (int v = 0; v < 4; ++v) {
        int off = (i0 + v) * 256 + j;
        if (useAtomic) atomicAdd(&Cp[off], acc[mf][nf][v]);
        else           Cp[off] = acc[mf][nf][v];
      }
    }
  }
}

// Sum P partials, z = dot/D, BCE vs identity labels:
//   diag: softplus(z) - z ; off-diag: softplus(z)
__global__ void __launch_bounds__(256)
loss_kernel(const float* __restrict__ ws, float* __restrict__ out, int P, float invD) {
  const int i = blockIdx.x, j = threadIdx.x;
  const float* base = ws + i * 256 + j;
  float s = 0.f;
#pragma unroll 8
  for (int p = 0; p < P; ++p) s += base[(size_t)p * 65536];
  float z = s * invD;
  float term = log1pf(expf(z)) - (i == j ? z : 0.f);

  __shared__ float red[256];
  red[j] = term;
  __syncthreads();
  for (int st = 128; st > 0; st >>= 1) {
    if (j < st) red[j] += red[j + st];
    __syncthreads();
  }
  if (j == 0) atomicAdd(out, red[0] * (1.f / 65536.f));
}

extern "C" void kernel_launch(void* const* d_in, const int* in_sizes, int n_in,
                              void* d_out, int out_size, void* d_ws, size_t ws_size,
                              hipStream_t stream) {
  const float* V1 = (const float*)d_in[0];
  const float* V2 = (const float*)d_in[1];
  float* out = (float*)d_out;
  float* ws  = (float*)d_ws;

  const int N = 256;
  const int D = in_sizes[0] / N;   // 262144
  const int KC = D / NBLK;         // 1024

  long long cap = (long long)(ws_size / (sizeof(float) * 65536));
  int P = (int)(cap >= NBLK ? NBLK : (cap < 1 ? 1 : cap));
  int useAtomic = (P < NBLK) ? 1 : 0;
  long long nws = useAtomic ? (long long)P * 65536 : 0;

  zero_kernel<<<64, 256, 0, stream>>>(out, ws, nws);
  gemm_kernel<<<NBLK, GEMM_THREADS, 0, stream>>>(V1, V2, ws, D, KC, P, useAtomic);
  loss_kernel<<<N, 256, 0, stream>>>(ws, out, P, 1.0f / (float)D);
}